// Round 3
// baseline (487.229 us; speedup 1.0000x reference)
//
#include <hip/hip_runtime.h>
#include <hip/hip_bf16.h>
#include <math.h>

// Shapes: B=8, L=1024, D_MODEL=256, D_INNER=1024, D_STATE=32, D_CONV=8, DT_RANK=16
// BL = 8192 token rows. All GEMMs run bf16 MFMA (16x16x32), fp32 accumulate.

typedef float          f32x4 __attribute__((ext_vector_type(4)));
typedef short          s16x8 __attribute__((ext_vector_type(8)));
typedef unsigned short u16;
typedef u16            u16x4 __attribute__((ext_vector_type(4)));

#define DEV __device__ __forceinline__

DEV float bf2f(u16 u) { unsigned int i = ((unsigned int)u) << 16; return __builtin_bit_cast(float, i); }
DEV u16 f2bf(float f) {
  unsigned int x = __builtin_bit_cast(unsigned int, f);
  unsigned int r = (x + 0x7FFFu + ((x >> 16) & 1u)) >> 16;   // RNE
  return (u16)r;
}
DEV float sigmoidf_(float x) { return 1.0f / (1.0f + __expf(-x)); }

// ---------------- small cast kernels ----------------
__global__ void k_cast(const float* __restrict__ s, u16* __restrict__ d, int n) {
  int i = blockIdx.x * 256 + threadIdx.x;
  if (i < n) d[i] = f2bf(s[i]);
}
// dt_proj_w (1024,16) -> bf16 (1024,32) zero-padded in K
__global__ void k_pad_dtw(const float* __restrict__ s, u16* __restrict__ d) {
  int i = blockIdx.x * 256 + threadIdx.x;   // 1024*32
  int row = i >> 5, k = i & 31;
  d[i] = (k < 16) ? f2bf(s[row * 16 + k]) : (u16)0;
}

// ---------------- LayerNorm: x fp32 (8192,256) -> xn bf16 ----------------
__global__ __launch_bounds__(256) void k_ln(const float* __restrict__ x,
    const float* __restrict__ w, const float* __restrict__ b, u16* __restrict__ xn) {
  int row  = blockIdx.x * 4 + (threadIdx.x >> 6);  // one wave per row
  int lane = threadIdx.x & 63;
  const float* xr = x + (size_t)row * 256 + lane * 4;
  f32x4 v = *(const f32x4*)xr;
  float s  = v[0] + v[1] + v[2] + v[3];
  float s2 = v[0]*v[0] + v[1]*v[1] + v[2]*v[2] + v[3]*v[3];
  for (int off = 32; off; off >>= 1) { s += __shfl_xor(s, off); s2 += __shfl_xor(s2, off); }
  float mu  = s * (1.0f / 256.0f);
  float inv = rsqrtf(s2 * (1.0f / 256.0f) - mu * mu + 1e-5f);
  int c = lane * 4;
  u16x4 o;
  #pragma unroll
  for (int t = 0; t < 4; ++t) o[t] = f2bf((v[t] - mu) * inv * w[c + t] + b[c + t]);
  *(u16x4*)(xn + (size_t)row * 256 + c) = o;
}

// ---------------- generic bf16 MFMA GEMM: C[M,N] = A[M,K] * W[N,K]^T ----------------
// EPI: 1 = bf16 out, 3 = acc + resid fp32,
//      4 = x_proj scatter: gc<16 -> dtbf bf16 [m][16]; 16<=gc<48 -> BC[b][n][l]; 48<=gc<80 -> BC[+1MB]
//      5 = dt_proj: v=softplus(acc+bias[gc]); deltaT[gc][gr]=v; gT[gc][gr]=v*u[gr][gc]
template<int WAVES_M, int WAVES_N, int WM, int WN, int EPI>
__global__ __launch_bounds__(WAVES_M * WAVES_N * 64)
void k_gemm(const u16* __restrict__ A, const u16* __restrict__ Bw,
            float* __restrict__ Cf, u16* __restrict__ Cb,
            const float* __restrict__ extra,
            int lda, int ldb, int ldc, int Ktiles, int Kact) {
  constexpr int BM = WAVES_M * WM * 16;
  constexpr int BN = WAVES_N * WN * 16;
  constexpr int BK = 32, LDP = BK + 8;            // +8 shorts: 80B row stride, kills bank conflicts
  constexpr int THREADS = WAVES_M * WAVES_N * 64;
  __shared__ u16 As[BM][LDP];
  __shared__ u16 Bs[BN][LDP];
  const int tid = threadIdx.x;
  const int m0 = blockIdx.x * BM, n0 = blockIdx.y * BN;
  const int w = tid >> 6, lane = tid & 63;
  const int wm = w / WAVES_N, wn = w % WAVES_N;
  const int r = lane & 15, kg = lane >> 4, ks = kg * 8;

  f32x4 acc[WM][WN] = {};

  for (int kt = 0; kt < Ktiles; ++kt) {
    const int k0 = kt * BK;
    for (int ci = tid; ci < BM * 4; ci += THREADS) {       // stage A tile (guarded for Kact<K)
      int row = ci >> 2, k8 = (ci & 3) * 8;
      s16x8 vv = {0, 0, 0, 0, 0, 0, 0, 0};
      if (k0 + k8 < Kact)
        vv = *(const s16x8*)(A + (size_t)(m0 + row) * lda + k0 + k8);
      *(s16x8*)(&As[row][k8]) = vv;
    }
    for (int ci = tid; ci < BN * 4; ci += THREADS) {       // stage B tile
      int row = ci >> 2, k8 = (ci & 3) * 8;
      *(s16x8*)(&Bs[row][k8]) = *(const s16x8*)(Bw + (size_t)(n0 + row) * ldb + k0 + k8);
    }
    __syncthreads();
    s16x8 af[WM], bfr[WN];
    #pragma unroll
    for (int i = 0; i < WM; ++i) af[i]  = *(const s16x8*)(&As[wm * WM * 16 + i * 16 + r][ks]);
    #pragma unroll
    for (int j = 0; j < WN; ++j) bfr[j] = *(const s16x8*)(&Bs[wn * WN * 16 + j * 16 + r][ks]);
    #pragma unroll
    for (int i = 0; i < WM; ++i)
      #pragma unroll
      for (int j = 0; j < WN; ++j)
        acc[i][j] = __builtin_amdgcn_mfma_f32_16x16x32_bf16(af[i], bfr[j], acc[i][j], 0, 0, 0);
    __syncthreads();
  }

  #pragma unroll
  for (int i = 0; i < WM; ++i)
    #pragma unroll
    for (int j = 0; j < WN; ++j)
      #pragma unroll
      for (int q = 0; q < 4; ++q) {
        int gr = m0 + wm * WM * 16 + i * 16 + kg * 4 + q;  // C/D: row=(lane>>4)*4+reg
        int gc = n0 + wn * WN * 16 + j * 16 + r;           //       col=lane&15
        float v = acc[i][j][q];
        size_t idx = (size_t)gr * ldc + gc;
        if constexpr (EPI == 1) Cb[idx] = f2bf(v);
        else if constexpr (EPI == 3) Cf[idx] = v + extra[idx];
        else if constexpr (EPI == 4) {
          int b_ = gr >> 10, l_ = gr & 1023;
          if (gc < 16)      Cb[(size_t)gr * 16 + gc] = f2bf(v);
          else if (gc < 48) Cf[(size_t)b_ * 32768 + (size_t)(gc - 16) * 1024 + l_] = v;
          else              Cf[262144 + (size_t)b_ * 32768 + (size_t)(gc - 48) * 1024 + l_] = v;
        } else if constexpr (EPI == 5) {
          v += extra[gc];
          v = (v > 20.0f) ? v : log1pf(expf(v));           // softplus -> delta
          size_t tidx = (size_t)gc * 8192 + gr;
          Cf[tidx] = v;                                     // deltaT[d][m]
          Cf[8388608 + tidx] = v * bf2f(Cb[(size_t)gr * 1024 + gc]);  // gT = delta*u
        }
      }
}

// ---------------- causal depthwise conv (K=8) + bias + SiLU ----------------
__global__ __launch_bounds__(256) void k_conv(const u16* __restrict__ xz,
    const float* __restrict__ cw, const float* __restrict__ cb, u16* __restrict__ u) {
  int d = (blockIdx.x & 3) * 256 + threadIdx.x;
  int m = blockIdx.x >> 2;
  int l = m & 1023;
  const f32x4* wv = (const f32x4*)(cw + (size_t)d * 8);
  f32x4 w0 = wv[0], w1 = wv[1];
  float acc = cb[d];
  #pragma unroll
  for (int j = 0; j < 8; ++j) {
    int li = l - 7 + j;
    float wj = (j < 4) ? w0[j] : w1[j - 4];
    if (li >= 0) acc = fmaf(bf2f(xz[(size_t)(m - 7 + j) * 2048 + d]), wj, acc);
  }
  u[(size_t)m * 1024 + d] = f2bf(acc * sigmoidf_(acc));
}

// ---------------- selective scan v3 ----------------
// Thread per (d,n). B/C staged in LDS (double-buffered, conflict-free, ds_read2-
// friendly). delta/g read as global f32x4 broadcasts from transposed deltaT/gT
// (produced by dt_proj epilogue; g = delta*u pre-multiplied). DPP 32-lane reduce.
template<int C, int RM, bool BC>
DEV float dpp_add(float x) {
  int s = __builtin_amdgcn_update_dpp(0, __builtin_bit_cast(int, x), C, RM, 0xf, BC);
  return x + __builtin_bit_cast(float, s);
}

__global__ __launch_bounds__(256) void k_scan(const float* __restrict__ deltaT,
    const float* __restrict__ gT, const float* __restrict__ BC,
    const float* __restrict__ A_log, float* __restrict__ y) {
  constexpr int CH = 64, NC = 1024 / CH;
  __shared__ float sB[2][CH][32];   // 16 KB
  __shared__ float sC[2][CH][32];   // 16 KB  (32 KB total -> 5 blocks/CU)
  const int b = blockIdx.x >> 7, dblk = blockIdx.x & 127;
  const int d0 = dblk * 8;
  const int t = threadIdx.x;
  const int n = t & 31, dloc = t >> 5;
  const int d = d0 + dloc;
  const float Adn = -__expf(A_log[d * 32 + n]) * 1.442695040888963f;  // fold log2e
  // staging mapping: BC[b][n][l], coalesced rows of 64 l's
  const int stRow = t >> 3, stL = (t & 7) * 8;   // 32 n-rows x 8 lanes x 8 l's per pass... (256 thr)
  const float* srcB = BC + (size_t)b * 32768;
  const float* srcC = BC + 262144 + (size_t)b * 32768;

  float rB[8], rC[8];
  auto load_chunk = [&](int c) {
    const int l0 = c * CH;
    #pragma unroll
    for (int i = 0; i < 8; ++i) {
      rB[i] = srcB[(size_t)stRow * 1024 + l0 + stL + i];
      rC[i] = srcC[(size_t)stRow * 1024 + l0 + stL + i];
    }
  };
  auto write_chunk = [&](int buf) {
    #pragma unroll
    for (int i = 0; i < 8; ++i) {
      sB[buf][stL + i][stRow] = rB[i];
      sC[buf][stL + i][stRow] = rC[i];
    }
  };

  load_chunk(0);
  write_chunk(0);
  __syncthreads();

  const float* dTp = deltaT + (size_t)d * 8192 + (size_t)b * 1024;
  const float* gTp = gT     + (size_t)d * 8192 + (size_t)b * 1024;
  float* yp = y + ((size_t)b * 1024) * 1024 + d;
  float h = 0.0f;
  const bool writer = ((t & 31) == 31);
  for (int c = 0; c < NC; ++c) {
    const int cur = c & 1;
    if (c + 1 < NC) load_chunk(c + 1);         // global loads in flight during compute
    const int l0c = c * CH;
    #pragma unroll 2
    for (int l4 = 0; l4 < CH; l4 += 4) {
      const int lg = l0c + l4;
      f32x4 dv4 = *(const f32x4*)(dTp + lg);   // 2 addrs/wave: TCP broadcast
      f32x4 g4  = *(const f32x4*)(gTp + lg);
      #pragma unroll
      for (int j = 0; j < 4; ++j) {
        float Bn = sB[cur][l4 + j][n];         // conflict-free, read2-mergeable
        float Cn = sC[cur][l4 + j][n];
        float dA = exp2f(dv4[j] * Adn);
        h = fmaf(dA, h, g4[j] * Bn);
        float p = h * Cn;
        p = dpp_add<0x111, 0xf, true >(p);     // row_shr 1/2/4/8 + bcast15
        p = dpp_add<0x112, 0xf, true >(p);
        p = dpp_add<0x114, 0xf, true >(p);
        p = dpp_add<0x118, 0xf, true >(p);
        p = dpp_add<0x142, 0xa, false>(p);
        if (writer) yp[(size_t)(lg + j) * 1024] = p;
      }
    }
    if (c + 1 < NC) {
      write_chunk(cur ^ 1);
      __syncthreads();
    }
  }
}

// ---------------- y_final = (y + u*D) * silu(z) -> bf16 ----------------
__global__ __launch_bounds__(256) void k_yfinal(const float* __restrict__ y,
    const u16* __restrict__ u, const u16* __restrict__ xz,
    const float* __restrict__ Dv, u16* __restrict__ yb) {
  int i = blockIdx.x * 256 + threadIdx.x;       // 8192*256 (4 elems each)
  int m = i >> 8, d = (i & 255) * 4;
  f32x4 yv = *(const f32x4*)(y + (size_t)m * 1024 + d);
  u16x4 uv = *(const u16x4*)(u + (size_t)m * 1024 + d);
  u16x4 zv = *(const u16x4*)(xz + (size_t)m * 2048 + 1024 + d);
  f32x4 Dw = *(const f32x4*)(Dv + d);
  u16x4 o;
  #pragma unroll
  for (int t = 0; t < 4; ++t) {
    float z = bf2f(zv[t]);
    float val = (yv[t] + bf2f(uv[t]) * Dw[t]) * (z * sigmoidf_(z));
    o[t] = f2bf(val);
  }
  *(u16x4*)(yb + (size_t)m * 1024 + d) = o;
}

extern "C" void kernel_launch(void* const* d_in, const int* in_sizes, int n_in,
                              void* d_out, int out_size, void* d_ws, size_t ws_size,
                              hipStream_t stream) {
  const float* x    = (const float*)d_in[0];
  const float* nw   = (const float*)d_in[1];
  const float* nb   = (const float*)d_in[2];
  const float* win  = (const float*)d_in[3];
  const float* cw   = (const float*)d_in[4];
  const float* cb   = (const float*)d_in[5];
  const float* wxp  = (const float*)d_in[6];
  const float* wdt  = (const float*)d_in[7];
  const float* dtb  = (const float*)d_in[8];
  const float* alog = (const float*)d_in[9];
  const float* Dv   = (const float*)d_in[10];
  const float* wout = (const float*)d_in[11];
  float* out = (float*)d_out;

  char* p = (char*)d_ws;
  auto alloc = [&](size_t bytes) { char* r = p; p += (bytes + 255) & ~(size_t)255; return r; };
  u16*   xn    = (u16*)  alloc((size_t)8192 * 256 * 2);
  u16*   winb  = (u16*)  alloc((size_t)2048 * 256 * 2);
  u16*   wxpb  = (u16*)  alloc((size_t)80 * 1024 * 2);
  u16*   wdtb  = (u16*)  alloc((size_t)1024 * 32 * 2);
  u16*   woutb = (u16*)  alloc((size_t)256 * 1024 * 2);
  u16*   xz    = (u16*)  alloc((size_t)8192 * 2048 * 2);  // [u | z] bf16
  u16*   ub    = (u16*)  alloc((size_t)8192 * 1024 * 2);  // silu(conv(u)) bf16
  u16*   dtbf  = (u16*)  alloc((size_t)8192 * 16 * 2);
  float* bcbuf = (float*)alloc((size_t)2 * 8 * 32 * 1024 * 4);   // Bt | Ct
  float* dTgT  = (float*)alloc((size_t)2 * 8192 * 1024 * 4);     // deltaT | gT (64 MB)
  float* ysc   = (float*)alloc((size_t)8192 * 1024 * 4);
  u16*   ybf   = (u16*)  alloc((size_t)8192 * 1024 * 2);

  // weight casts (every call: ws is re-poisoned)
  k_cast<<<2048, 256, 0, stream>>>(win, winb, 2048 * 256);
  k_cast<<<320, 256, 0, stream>>>(wxp, wxpb, 80 * 1024);
  k_pad_dtw<<<128, 256, 0, stream>>>(wdt, wdtb);
  k_cast<<<1024, 256, 0, stream>>>(wout, woutb, 256 * 1024);

  // 1. LayerNorm
  k_ln<<<2048, 256, 0, stream>>>(x, nw, nb, xn);
  // 2. in_proj: (8192,256)x(2048,256)^T -> xz bf16 (8192,2048)
  k_gemm<2, 2, 4, 4, 1><<<dim3(64, 16), 256, 0, stream>>>(xn, winb, nullptr, xz, nullptr,
                                                          256, 256, 2048, 8, 256);
  // 3. conv + SiLU -> u bf16 (8192,1024)
  k_conv<<<32768, 256, 0, stream>>>(xz, cw, cb, ub);
  // 4. x_proj: (8192,1024)x(80,1024)^T -> dtbf bf16 + BC[b][n][l] fp32
  k_gemm<2, 1, 1, 5, 4><<<dim3(256, 1), 128, 0, stream>>>(ub, wxpb, bcbuf, dtbf, nullptr,
                                                          1024, 1024, 80, 32, 1024);
  // 5. dt_proj (K=16 padded to 32) + softplus -> deltaT[d][m], gT[d][m]=delta*u
  k_gemm<2, 2, 4, 4, 5><<<dim3(64, 8), 256, 0, stream>>>(dtbf, wdtb, dTgT, ub, dtb,
                                                         16, 32, 8192, 1, 16);
  // 6. selective scan -> y fp32 (8192,1024)
  k_scan<<<1024, 256, 0, stream>>>(dTgT, dTgT + 8388608, bcbuf, alog, ysc);
  // 7. (y + u*D) * silu(z) -> bf16
  k_yfinal<<<8192, 256, 0, stream>>>(ysc, ub, xz, Dv, ybf);
  // 8. out_proj + residual -> d_out fp32 (8192,256)
  k_gemm<2, 2, 2, 2, 3><<<dim3(128, 4), 256, 0, stream>>>(ybf, woutb, out, nullptr, x,
                                                          1024, 1024, 256, 32, 1024);
}

// Round 5
// 449.206 us; speedup vs baseline: 1.0846x; 1.0846x over previous
//
#include <hip/hip_runtime.h>
#include <hip/hip_bf16.h>
#include <math.h>

// Shapes: B=8, L=1024, D_MODEL=256, D_INNER=1024, D_STATE=32, D_CONV=8, DT_RANK=16
// BL = 8192 token rows. All GEMMs run bf16 MFMA (16x16x32), fp32 accumulate.

typedef float          f32x4 __attribute__((ext_vector_type(4)));
typedef float          f32x2 __attribute__((ext_vector_type(2)));
typedef short          s16x8 __attribute__((ext_vector_type(8)));
typedef unsigned short u16;
typedef u16            u16x4 __attribute__((ext_vector_type(4)));

#define DEV __device__ __forceinline__

DEV float bf2f(u16 u) { unsigned int i = ((unsigned int)u) << 16; return __builtin_bit_cast(float, i); }
DEV u16 f2bf(float f) {
  unsigned int x = __builtin_bit_cast(unsigned int, f);
  unsigned int r = (x + 0x7FFFu + ((x >> 16) & 1u)) >> 16;   // RNE
  return (u16)r;
}
DEV float sigmoidf_(float x) { return 1.0f / (1.0f + __expf(-x)); }

// ---------------- small cast kernels ----------------
__global__ void k_cast(const float* __restrict__ s, u16* __restrict__ d, int n) {
  int i = blockIdx.x * 256 + threadIdx.x;
  if (i < n) d[i] = f2bf(s[i]);
}
// dt_proj_w (1024,16) -> bf16 (1024,32) zero-padded in K
__global__ void k_pad_dtw(const float* __restrict__ s, u16* __restrict__ d) {
  int i = blockIdx.x * 256 + threadIdx.x;   // 1024*32
  int row = i >> 5, k = i & 31;
  d[i] = (k < 16) ? f2bf(s[row * 16 + k]) : (u16)0;
}

// ---------------- LayerNorm: x fp32 (8192,256) -> xn bf16 ----------------
__global__ __launch_bounds__(256) void k_ln(const float* __restrict__ x,
    const float* __restrict__ w, const float* __restrict__ b, u16* __restrict__ xn) {
  int row  = blockIdx.x * 4 + (threadIdx.x >> 6);  // one wave per row
  int lane = threadIdx.x & 63;
  const float* xr = x + (size_t)row * 256 + lane * 4;
  f32x4 v = *(const f32x4*)xr;
  float s  = v[0] + v[1] + v[2] + v[3];
  float s2 = v[0]*v[0] + v[1]*v[1] + v[2]*v[2] + v[3]*v[3];
  for (int off = 32; off; off >>= 1) { s += __shfl_xor(s, off); s2 += __shfl_xor(s2, off); }
  float mu  = s * (1.0f / 256.0f);
  float inv = rsqrtf(s2 * (1.0f / 256.0f) - mu * mu + 1e-5f);
  int c = lane * 4;
  u16x4 o;
  #pragma unroll
  for (int t = 0; t < 4; ++t) o[t] = f2bf((v[t] - mu) * inv * w[c + t] + b[c + t]);
  *(u16x4*)(xn + (size_t)row * 256 + c) = o;
}

// ---------------- generic bf16 MFMA GEMM: C[M,N] = A[M,K] * W[N,K]^T ----------------
// EPI: 1 = bf16 out, 3 = acc + resid fp32,
//      4 = x_proj scatter: gc<16 -> dtbf bf16 [m][16]; 16<=gc<48 -> BC[b][l][2(gc-16)];
//          48<=gc<80 -> BC[b][l][2(gc-48)+1]   (B,C interleaved, l-major)
//      5 = dt_proj: v=softplus(acc+bias); deltaT[d][m]=v; gT[d][m]=v*u[m][d] (f32x4 stores)
template<int WAVES_M, int WAVES_N, int WM, int WN, int EPI>
__global__ __launch_bounds__(WAVES_M * WAVES_N * 64)
void k_gemm(const u16* __restrict__ A, const u16* __restrict__ Bw,
            float* __restrict__ Cf, u16* __restrict__ Cb,
            const float* __restrict__ extra,
            int lda, int ldb, int ldc, int Ktiles, int Kact) {
  constexpr int BM = WAVES_M * WM * 16;
  constexpr int BN = WAVES_N * WN * 16;
  constexpr int BK = 32, LDP = BK + 8;            // +8 shorts: 80B row stride, kills bank conflicts
  constexpr int THREADS = WAVES_M * WAVES_N * 64;
  __shared__ u16 As[BM][LDP];
  __shared__ u16 Bs[BN][LDP];
  const int tid = threadIdx.x;
  const int m0 = blockIdx.x * BM, n0 = blockIdx.y * BN;
  const int w = tid >> 6, lane = tid & 63;
  const int wm = w / WAVES_N, wn = w % WAVES_N;
  const int r = lane & 15, kg = lane >> 4, ks = kg * 8;

  f32x4 acc[WM][WN] = {};

  for (int kt = 0; kt < Ktiles; ++kt) {
    const int k0 = kt * BK;
    for (int ci = tid; ci < BM * 4; ci += THREADS) {       // stage A tile (guarded for Kact<K)
      int row = ci >> 2, k8 = (ci & 3) * 8;
      s16x8 vv = {0, 0, 0, 0, 0, 0, 0, 0};
      if (k0 + k8 < Kact)
        vv = *(const s16x8*)(A + (size_t)(m0 + row) * lda + k0 + k8);
      *(s16x8*)(&As[row][k8]) = vv;
    }
    for (int ci = tid; ci < BN * 4; ci += THREADS) {       // stage B tile
      int row = ci >> 2, k8 = (ci & 3) * 8;
      *(s16x8*)(&Bs[row][k8]) = *(const s16x8*)(Bw + (size_t)(n0 + row) * ldb + k0 + k8);
    }
    __syncthreads();
    s16x8 af[WM], bfr[WN];
    #pragma unroll
    for (int i = 0; i < WM; ++i) af[i]  = *(const s16x8*)(&As[wm * WM * 16 + i * 16 + r][ks]);
    #pragma unroll
    for (int j = 0; j < WN; ++j) bfr[j] = *(const s16x8*)(&Bs[wn * WN * 16 + j * 16 + r][ks]);
    #pragma unroll
    for (int i = 0; i < WM; ++i)
      #pragma unroll
      for (int j = 0; j < WN; ++j)
        acc[i][j] = __builtin_amdgcn_mfma_f32_16x16x32_bf16(af[i], bfr[j], acc[i][j], 0, 0, 0);
    __syncthreads();
  }

  if constexpr (EPI == 5) {
    #pragma unroll
    for (int i = 0; i < WM; ++i)
      #pragma unroll
      for (int j = 0; j < WN; ++j) {
        int m_base = m0 + wm * WM * 16 + i * 16 + kg * 4;
        int d_ = n0 + wn * WN * 16 + j * 16 + r;
        f32x4 dlt, gv;
        #pragma unroll
        for (int q = 0; q < 4; ++q) {
          float v = acc[i][j][q] + extra[d_];
          v = (v > 20.0f) ? v : log1pf(expf(v));           // softplus
          dlt[q] = v;
          gv[q] = v * bf2f(Cb[(size_t)(m_base + q) * 1024 + d_]);
        }
        size_t tidx = (size_t)d_ * 8192 + m_base;
        *(f32x4*)(Cf + tidx) = dlt;                        // deltaT[d][m]
        *(f32x4*)(Cf + 8388608 + tidx) = gv;               // gT[d][m]
      }
  } else {
    #pragma unroll
    for (int i = 0; i < WM; ++i)
      #pragma unroll
      for (int j = 0; j < WN; ++j)
        #pragma unroll
        for (int q = 0; q < 4; ++q) {
          int gr = m0 + wm * WM * 16 + i * 16 + kg * 4 + q;  // C/D: row=(lane>>4)*4+reg
          int gc = n0 + wn * WN * 16 + j * 16 + r;           //       col=lane&15
          float v = acc[i][j][q];
          size_t idx = (size_t)gr * ldc + gc;
          if constexpr (EPI == 1) Cb[idx] = f2bf(v);
          else if constexpr (EPI == 3) Cf[idx] = v + extra[idx];
          else if constexpr (EPI == 4) {
            int b_ = gr >> 10, l_ = gr & 1023;
            if (gc < 16)      Cb[(size_t)gr * 16 + gc] = f2bf(v);
            else if (gc < 48) Cf[(size_t)b_ * 65536 + (size_t)l_ * 64 + (gc - 16) * 2] = v;
            else              Cf[(size_t)b_ * 65536 + (size_t)l_ * 64 + (gc - 48) * 2 + 1] = v;
          }
        }
  }
}

// ---------------- causal depthwise conv (K=8) + bias + SiLU ----------------
__global__ __launch_bounds__(256) void k_conv(const u16* __restrict__ xz,
    const float* __restrict__ cw, const float* __restrict__ cb, u16* __restrict__ u) {
  int d = (blockIdx.x & 3) * 256 + threadIdx.x;
  int m = blockIdx.x >> 2;
  int l = m & 1023;
  const f32x4* wv = (const f32x4*)(cw + (size_t)d * 8);
  f32x4 w0 = wv[0], w1 = wv[1];
  float acc = cb[d];
  #pragma unroll
  for (int j = 0; j < 8; ++j) {
    int li = l - 7 + j;
    float wj = (j < 4) ? w0[j] : w1[j - 4];
    if (li >= 0) acc = fmaf(bf2f(xz[(size_t)(m - 7 + j) * 2048 + d]), wj, acc);
  }
  u[(size_t)m * 1024 + d] = f2bf(acc * sigmoidf_(acc));
}

// ---------------- selective scan v4 ----------------
// Thread per (d,n). B/C interleaved [b][l][2n] fp32, staged via double-buffered
// LDS (ds_write_b64 / ds_read_b64, 2-way bank alias = free). delta/g read as
// global f32x4 broadcasts from deltaT/gT with depth-1 register prefetch.
// DPP 32-lane reduce for y = sum_n h*C.
template<int C, int RM, bool BC>
DEV float dpp_add(float x) {
  int s = __builtin_amdgcn_update_dpp(0, __builtin_bit_cast(int, x), C, RM, 0xf, BC);
  return x + __builtin_bit_cast(float, s);
}

__global__ __launch_bounds__(256) void k_scan(const float* __restrict__ deltaT,
    const float* __restrict__ gT, const float* __restrict__ BC,
    const float* __restrict__ A_log, float* __restrict__ y) {
  constexpr int CH = 64, NC = 1024 / CH;
  __shared__ float sBC[2][CH][64];    // {B,C} interleaved; 32 KB
  const int b = blockIdx.x >> 7, dblk = blockIdx.x & 127;
  const int d0 = dblk * 8;
  const int t = threadIdx.x;
  const int n = t & 31, dloc = t >> 5;
  const int d = d0 + dloc;
  const float Adn = -__expf(A_log[d * 32 + n]) * 1.442695040888963f;  // fold log2e
  // staging: one l-row = 64 consecutive floats; 256 threads cover 8 rows/pass via f32x2
  const int stRow = t >> 5;           // l-row within pass (0..7)
  const int stCol = (t & 31) * 2;     // even float index within row
  const float* src = BC + (size_t)b * 65536;

  f32x2 rr[8];
  auto load_chunk = [&](int c) {
    const int l0 = c * CH;
    #pragma unroll
    for (int i = 0; i < 8; ++i)
      rr[i] = *(const f32x2*)(src + (size_t)(l0 + stRow + 8 * i) * 64 + stCol);
  };
  auto write_chunk = [&](int buf) {
    #pragma unroll
    for (int i = 0; i < 8; ++i)
      *(f32x2*)(&sBC[buf][stRow + 8 * i][stCol]) = rr[i];   // bank 2n: 2-way, free
  };

  load_chunk(0);
  write_chunk(0);
  __syncthreads();

  const float* dTp = deltaT + (size_t)d * 8192 + (size_t)b * 1024;
  const float* gTp = gT     + (size_t)d * 8192 + (size_t)b * 1024;
  float* yp = y + ((size_t)b * 1024) * 1024 + d;
  float h = 0.0f;
  const bool writer = ((t & 31) == 31);
  f32x4 dv4 = *(const f32x4*)(dTp);        // group prefetch (depth 1)
  f32x4 g4  = *(const f32x4*)(gTp);
  for (int c = 0; c < NC; ++c) {
    const int cur = c & 1;
    if (c + 1 < NC) load_chunk(c + 1);     // chunk staging loads in flight during compute
    const int l0c = c * CH;
    for (int l4 = 0; l4 < CH; l4 += 4) {
      const int lg = l0c + l4;
      f32x4 dv4n = dv4, g4n = g4;
      if (lg + 4 < 1024) {
        dv4n = *(const f32x4*)(dTp + lg + 4);
        g4n  = *(const f32x4*)(gTp + lg + 4);
      }
      #pragma unroll
      for (int j = 0; j < 4; ++j) {
        f32x2 bc = *(const f32x2*)(&sBC[cur][l4 + j][2 * n]);  // one b64: B and C
        float dA = exp2f(dv4[j] * Adn);
        h = fmaf(dA, h, g4[j] * bc[0]);
        float p = h * bc[1];
        p = dpp_add<0x111, 0xf, true >(p);     // row_shr 1/2/4/8 + bcast15
        p = dpp_add<0x112, 0xf, true >(p);
        p = dpp_add<0x114, 0xf, true >(p);
        p = dpp_add<0x118, 0xf, true >(p);
        p = dpp_add<0x142, 0xa, false>(p);
        if (writer) yp[(size_t)(lg + j) * 1024] = p;
      }
      dv4 = dv4n; g4 = g4n;
    }
    if (c + 1 < NC) {
      write_chunk(cur ^ 1);
      __syncthreads();
    }
  }
}

// ---------------- y_final = (y + u*D) * silu(z) -> bf16 ----------------
__global__ __launch_bounds__(256) void k_yfinal(const float* __restrict__ y,
    const u16* __restrict__ u, const u16* __restrict__ xz,
    const float* __restrict__ Dv, u16* __restrict__ yb) {
  int i = blockIdx.x * 256 + threadIdx.x;       // 8192*256 (4 elems each)
  int m = i >> 8, d = (i & 255) * 4;
  f32x4 yv = *(const f32x4*)(y + (size_t)m * 1024 + d);
  u16x4 uv = *(const u16x4*)(u + (size_t)m * 1024 + d);
  u16x4 zv = *(const u16x4*)(xz + (size_t)m * 2048 + 1024 + d);
  f32x4 Dw = *(const f32x4*)(Dv + d);
  u16x4 o;
  #pragma unroll
  for (int t = 0; t < 4; ++t) {
    float z = bf2f(zv[t]);
    float val = (yv[t] + bf2f(uv[t]) * Dw[t]) * (z * sigmoidf_(z));
    o[t] = f2bf(val);
  }
  *(u16x4*)(yb + (size_t)m * 1024 + d) = o;
}

extern "C" void kernel_launch(void* const* d_in, const int* in_sizes, int n_in,
                              void* d_out, int out_size, void* d_ws, size_t ws_size,
                              hipStream_t stream) {
  const float* x    = (const float*)d_in[0];
  const float* nw   = (const float*)d_in[1];
  const float* nb   = (const float*)d_in[2];
  const float* win  = (const float*)d_in[3];
  const float* cw   = (const float*)d_in[4];
  const float* cb   = (const float*)d_in[5];
  const float* wxp  = (const float*)d_in[6];
  const float* wdt  = (const float*)d_in[7];
  const float* dtb  = (const float*)d_in[8];
  const float* alog = (const float*)d_in[9];
  const float* Dv   = (const float*)d_in[10];
  const float* wout = (const float*)d_in[11];
  float* out = (float*)d_out;

  char* p = (char*)d_ws;
  auto alloc = [&](size_t bytes) { char* r = p; p += (bytes + 255) & ~(size_t)255; return r; };
  u16*   xn    = (u16*)  alloc((size_t)8192 * 256 * 2);
  u16*   winb  = (u16*)  alloc((size_t)2048 * 256 * 2);
  u16*   wxpb  = (u16*)  alloc((size_t)80 * 1024 * 2);
  u16*   wdtb  = (u16*)  alloc((size_t)1024 * 32 * 2);
  u16*   woutb = (u16*)  alloc((size_t)256 * 1024 * 2);
  u16*   xz    = (u16*)  alloc((size_t)8192 * 2048 * 2);  // [u | z] bf16
  u16*   ub    = (u16*)  alloc((size_t)8192 * 1024 * 2);  // silu(conv(u)) bf16
  u16*   dtbf  = (u16*)  alloc((size_t)8192 * 16 * 2);
  float* bcbuf = (float*)alloc((size_t)8 * 1024 * 64 * 4);       // [b][l][2n] B,C interleaved
  float* dTgT  = (float*)alloc((size_t)2 * 8192 * 1024 * 4);     // deltaT | gT (64 MB)
  float* ysc   = (float*)alloc((size_t)8192 * 1024 * 4);
  u16*   ybf   = (u16*)  alloc((size_t)8192 * 1024 * 2);

  // weight casts (every call: ws is re-poisoned)
  k_cast<<<2048, 256, 0, stream>>>(win, winb, 2048 * 256);
  k_cast<<<320, 256, 0, stream>>>(wxp, wxpb, 80 * 1024);
  k_pad_dtw<<<128, 256, 0, stream>>>(wdt, wdtb);
  k_cast<<<1024, 256, 0, stream>>>(wout, woutb, 256 * 1024);

  // 1. LayerNorm
  k_ln<<<2048, 256, 0, stream>>>(x, nw, nb, xn);
  // 2. in_proj: (8192,256)x(2048,256)^T -> xz bf16 (8192,2048)
  k_gemm<2, 2, 4, 4, 1><<<dim3(64, 16), 256, 0, stream>>>(xn, winb, nullptr, xz, nullptr,
                                                          256, 256, 2048, 8, 256);
  // 3. conv + SiLU -> u bf16 (8192,1024)
  k_conv<<<32768, 256, 0, stream>>>(xz, cw, cb, ub);
  // 4. x_proj: (8192,1024)x(80,1024)^T -> dtbf bf16 + BC[b][l][2n] fp32
  k_gemm<2, 1, 1, 5, 4><<<dim3(256, 1), 128, 0, stream>>>(ub, wxpb, bcbuf, dtbf, nullptr,
                                                          1024, 1024, 80, 32, 1024);
  // 5. dt_proj (K=16 padded to 32) + softplus -> deltaT[d][m], gT[d][m]=delta*u
  k_gemm<2, 2, 4, 4, 5><<<dim3(64, 8), 256, 0, stream>>>(dtbf, wdtb, dTgT, ub, dtb,
                                                         16, 32, 8192, 1, 16);
  // 6. selective scan -> y fp32 (8192,1024)
  k_scan<<<1024, 256, 0, stream>>>(dTgT, dTgT + 8388608, bcbuf, alog, ysc);
  // 7. (y + u*D) * silu(z) -> bf16
  k_yfinal<<<8192, 256, 0, stream>>>(ysc, ub, xz, Dv, ybf);
  // 8. out_proj + residual -> d_out fp32 (8192,256)
  k_gemm<2, 2, 2, 2, 3><<<dim3(128, 4), 256, 0, stream>>>(ybf, woutb, out, nullptr, x,
                                                          1024, 1024, 256, 32, 1024);
}

// Round 7
// 413.180 us; speedup vs baseline: 1.1792x; 1.0872x over previous
//
#include <hip/hip_runtime.h>
#include <hip/hip_bf16.h>
#include <math.h>

// Shapes: B=8, L=1024, D_MODEL=256, D_INNER=1024, D_STATE=32, D_CONV=8, DT_RANK=16
// BL = 8192 token rows. All GEMMs run bf16 MFMA (16x16x32), fp32 accumulate.

typedef float          f32x4 __attribute__((ext_vector_type(4)));
typedef float          f32x2 __attribute__((ext_vector_type(2)));
typedef short          s16x8 __attribute__((ext_vector_type(8)));
typedef unsigned short u16;
typedef u16            u16x4 __attribute__((ext_vector_type(4)));

#define DEV __device__ __forceinline__

DEV float bf2f(u16 u) { unsigned int i = ((unsigned int)u) << 16; return __builtin_bit_cast(float, i); }
DEV u16 f2bf(float f) {
  unsigned int x = __builtin_bit_cast(unsigned int, f);
  unsigned int r = (x + 0x7FFFu + ((x >> 16) & 1u)) >> 16;   // RNE
  return (u16)r;
}
DEV float sigmoidf_(float x) { return 1.0f / (1.0f + __expf(-x)); }

// ---------------- small cast kernels ----------------
__global__ void k_cast(const float* __restrict__ s, u16* __restrict__ d, int n) {
  int i = blockIdx.x * 256 + threadIdx.x;
  if (i < n) d[i] = f2bf(s[i]);
}
// dt_proj_w (1024,16) -> bf16 (1024,32) zero-padded in K
__global__ void k_pad_dtw(const float* __restrict__ s, u16* __restrict__ d) {
  int i = blockIdx.x * 256 + threadIdx.x;   // 1024*32
  int row = i >> 5, k = i & 31;
  d[i] = (k < 16) ? f2bf(s[row * 16 + k]) : (u16)0;
}

// ---------------- LayerNorm: x fp32 (8192,256) -> xn bf16 ----------------
__global__ __launch_bounds__(256) void k_ln(const float* __restrict__ x,
    const float* __restrict__ w, const float* __restrict__ b, u16* __restrict__ xn) {
  int row  = blockIdx.x * 4 + (threadIdx.x >> 6);  // one wave per row
  int lane = threadIdx.x & 63;
  const float* xr = x + (size_t)row * 256 + lane * 4;
  f32x4 v = *(const f32x4*)xr;
  float s  = v[0] + v[1] + v[2] + v[3];
  float s2 = v[0]*v[0] + v[1]*v[1] + v[2]*v[2] + v[3]*v[3];
  for (int off = 32; off; off >>= 1) { s += __shfl_xor(s, off); s2 += __shfl_xor(s2, off); }
  float mu  = s * (1.0f / 256.0f);
  float inv = rsqrtf(s2 * (1.0f / 256.0f) - mu * mu + 1e-5f);
  int c = lane * 4;
  u16x4 o;
  #pragma unroll
  for (int t = 0; t < 4; ++t) o[t] = f2bf((v[t] - mu) * inv * w[c + t] + b[c + t]);
  *(u16x4*)(xn + (size_t)row * 256 + c) = o;
}

// ---------------- generic bf16 MFMA GEMM: C[M,N] = A[M,K] * W[N,K]^T ----------------
// EPI: 1 = bf16 out, 3 = acc + resid fp32,
//      4 = x_proj scatter: gc<16 -> dtbf bf16 [m][16];
//          16<=gc<48 (B, n=gc-16) -> BC[b][l][4*(n>>1) + (n&1)];
//          48<=gc<80 (C, n=gc-48) -> BC[b][l][4*(n>>1) + 2 + (n&1)]
//          (pair-interleaved rows: [B2k, B2k+1, C2k, C2k+1], k=0..15)
//      5 = dt_proj: v=softplus(acc+bias); deltaT[d][m]=v; gT[d][m]=v*u[m][d] (f32x4 stores)
template<int WAVES_M, int WAVES_N, int WM, int WN, int EPI>
__global__ __launch_bounds__(WAVES_M * WAVES_N * 64)
void k_gemm(const u16* __restrict__ A, const u16* __restrict__ Bw,
            float* __restrict__ Cf, u16* __restrict__ Cb,
            const float* __restrict__ extra,
            int lda, int ldb, int ldc, int Ktiles, int Kact) {
  constexpr int BM = WAVES_M * WM * 16;
  constexpr int BN = WAVES_N * WN * 16;
  constexpr int BK = 32, LDP = BK + 8;            // +8 shorts: 80B row stride, kills bank conflicts
  constexpr int THREADS = WAVES_M * WAVES_N * 64;
  __shared__ u16 As[BM][LDP];
  __shared__ u16 Bs[BN][LDP];
  const int tid = threadIdx.x;
  const int m0 = blockIdx.x * BM, n0 = blockIdx.y * BN;
  const int w = tid >> 6, lane = tid & 63;
  const int wm = w / WAVES_N, wn = w % WAVES_N;
  const int r = lane & 15, kg = lane >> 4, ks = kg * 8;

  f32x4 acc[WM][WN] = {};

  for (int kt = 0; kt < Ktiles; ++kt) {
    const int k0 = kt * BK;
    for (int ci = tid; ci < BM * 4; ci += THREADS) {       // stage A tile (guarded for Kact<K)
      int row = ci >> 2, k8 = (ci & 3) * 8;
      s16x8 vv = {0, 0, 0, 0, 0, 0, 0, 0};
      if (k0 + k8 < Kact)
        vv = *(const s16x8*)(A + (size_t)(m0 + row) * lda + k0 + k8);
      *(s16x8*)(&As[row][k8]) = vv;
    }
    for (int ci = tid; ci < BN * 4; ci += THREADS) {       // stage B tile
      int row = ci >> 2, k8 = (ci & 3) * 8;
      *(s16x8*)(&Bs[row][k8]) = *(const s16x8*)(Bw + (size_t)(n0 + row) * ldb + k0 + k8);
    }
    __syncthreads();
    s16x8 af[WM], bfr[WN];
    #pragma unroll
    for (int i = 0; i < WM; ++i) af[i]  = *(const s16x8*)(&As[wm * WM * 16 + i * 16 + r][ks]);
    #pragma unroll
    for (int j = 0; j < WN; ++j) bfr[j] = *(const s16x8*)(&Bs[wn * WN * 16 + j * 16 + r][ks]);
    #pragma unroll
    for (int i = 0; i < WM; ++i)
      #pragma unroll
      for (int j = 0; j < WN; ++j)
        acc[i][j] = __builtin_amdgcn_mfma_f32_16x16x32_bf16(af[i], bfr[j], acc[i][j], 0, 0, 0);
    __syncthreads();
  }

  if constexpr (EPI == 5) {
    #pragma unroll
    for (int i = 0; i < WM; ++i)
      #pragma unroll
      for (int j = 0; j < WN; ++j) {
        int m_base = m0 + wm * WM * 16 + i * 16 + kg * 4;
        int d_ = n0 + wn * WN * 16 + j * 16 + r;
        f32x4 dlt, gv;
        #pragma unroll
        for (int q = 0; q < 4; ++q) {
          float v = acc[i][j][q] + extra[d_];
          v = (v > 20.0f) ? v : log1pf(expf(v));           // softplus
          dlt[q] = v;
          gv[q] = v * bf2f(Cb[(size_t)(m_base + q) * 1024 + d_]);
        }
        size_t tidx = (size_t)d_ * 8192 + m_base;
        *(f32x4*)(Cf + tidx) = dlt;                        // deltaT[d][m]
        *(f32x4*)(Cf + 8388608 + tidx) = gv;               // gT[d][m]
      }
  } else {
    #pragma unroll
    for (int i = 0; i < WM; ++i)
      #pragma unroll
      for (int j = 0; j < WN; ++j)
        #pragma unroll
        for (int q = 0; q < 4; ++q) {
          int gr = m0 + wm * WM * 16 + i * 16 + kg * 4 + q;  // C/D: row=(lane>>4)*4+reg
          int gc = n0 + wn * WN * 16 + j * 16 + r;           //       col=lane&15
          float v = acc[i][j][q];
          size_t idx = (size_t)gr * ldc + gc;
          if constexpr (EPI == 1) Cb[idx] = f2bf(v);
          else if constexpr (EPI == 3) Cf[idx] = v + extra[idx];
          else if constexpr (EPI == 4) {
            int b_ = gr >> 10, l_ = gr & 1023;
            if (gc < 16)      Cb[(size_t)gr * 16 + gc] = f2bf(v);
            else if (gc < 48) {
              int n_ = gc - 16;
              Cf[(size_t)b_ * 65536 + (size_t)l_ * 64 + 4 * (n_ >> 1) + (n_ & 1)] = v;
            } else {
              int n_ = gc - 48;
              Cf[(size_t)b_ * 65536 + (size_t)l_ * 64 + 4 * (n_ >> 1) + 2 + (n_ & 1)] = v;
            }
          }
        }
  }
}

// ---------------- causal depthwise conv (K=8) + bias + SiLU ----------------
__global__ __launch_bounds__(256) void k_conv(const u16* __restrict__ xz,
    const float* __restrict__ cw, const float* __restrict__ cb, u16* __restrict__ u) {
  int d = (blockIdx.x & 3) * 256 + threadIdx.x;
  int m = blockIdx.x >> 2;
  int l = m & 1023;
  const f32x4* wv = (const f32x4*)(cw + (size_t)d * 8);
  f32x4 w0 = wv[0], w1 = wv[1];
  float acc = cb[d];
  #pragma unroll
  for (int j = 0; j < 8; ++j) {
    int li = l - 7 + j;
    float wj = (j < 4) ? w0[j] : w1[j - 4];
    if (li >= 0) acc = fmaf(bf2f(xz[(size_t)(m - 7 + j) * 2048 + d]), wj, acc);
  }
  u[(size_t)m * 1024 + d] = f2bf(acc * sigmoidf_(acc));
}

// ---------------- selective scan v5 ----------------
// Thread owns (d, n-pair): 2 h-chains per thread (2x ILP), 16 lanes per d,
// 4 d's per wave. Per l: one ds_read_b128 {B0,B1,C0,C1}, 2 exp2, 2 fma-chains,
// in-thread pair combine, 4-step DPP reduce over 16 lanes. B/C staged in
// double-buffered LDS; delta/g are global f32x4 broadcasts from deltaT/gT
// (dt_proj epilogue output; g = delta*u pre-multiplied) with depth-1 prefetch.
template<int C, int RM, bool BC>
DEV float dpp_add(float x) {
  int s = __builtin_amdgcn_update_dpp(0, __builtin_bit_cast(int, x), C, RM, 0xf, BC);
  return x + __builtin_bit_cast(float, s);
}

__global__ __launch_bounds__(256) void k_scan(const float* __restrict__ deltaT,
    const float* __restrict__ gT, const float* __restrict__ BC,
    const float* __restrict__ A_log, float* __restrict__ y) {
  constexpr int CH = 64, NC = 1024 / CH;
  __shared__ float sBC[2][CH][64];    // per l: [B2k,B2k+1,C2k,C2k+1] k=0..15; 32 KB
  const int b = blockIdx.x >> 6, dblk = blockIdx.x & 63;
  const int t = threadIdx.x;
  const int k16 = t & 15;             // n-pair index: n = {2*k16, 2*k16+1}
  const int dloc = t >> 4;            // 0..15
  const int d = dblk * 16 + dloc;
  const float LOG2E = 1.442695040888963f;
  const float Adn0 = -__expf(A_log[d * 32 + 2 * k16])     * LOG2E;
  const float Adn1 = -__expf(A_log[d * 32 + 2 * k16 + 1]) * LOG2E;
  // staging: one l-row = 64 consecutive floats; 256 threads cover 8 rows/pass via f32x2
  const int stRow = t >> 5;           // l-row within pass (0..7)
  const int stCol = (t & 31) * 2;     // even float index within row
  const float* src = BC + (size_t)b * 65536;

  f32x2 rr[8];
  auto load_chunk = [&](int c) {
    const int l0 = c * CH;
    #pragma unroll
    for (int i = 0; i < 8; ++i)
      rr[i] = *(const f32x2*)(src + (size_t)(l0 + stRow + 8 * i) * 64 + stCol);
  };
  auto write_chunk = [&](int buf) {
    #pragma unroll
    for (int i = 0; i < 8; ++i)
      *(f32x2*)(&sBC[buf][stRow + 8 * i][stCol]) = rr[i];   // bank 2n: 2-way, free
  };

  load_chunk(0);
  write_chunk(0);
  __syncthreads();

  const float* dTp = deltaT + (size_t)d * 8192 + (size_t)b * 1024;
  const float* gTp = gT     + (size_t)d * 8192 + (size_t)b * 1024;
  float* yp = y + ((size_t)b * 1024) * 1024 + d;
  float h0 = 0.0f, h1 = 0.0f;
  const bool writer = (k16 == 15);
  f32x4 dv4 = *(const f32x4*)(dTp);        // group prefetch (depth 1)
  f32x4 g4  = *(const f32x4*)(gTp);
  for (int c = 0; c < NC; ++c) {
    const int cur = c & 1;
    if (c + 1 < NC) load_chunk(c + 1);     // chunk staging loads in flight during compute
    const int l0c = c * CH;
    for (int l4 = 0; l4 < CH; l4 += 4) {
      const int lg = l0c + l4;
      f32x4 dv4n = dv4, g4n = g4;
      if (lg + 4 < 1024) {
        dv4n = *(const f32x4*)(dTp + lg + 4);
        g4n  = *(const f32x4*)(gTp + lg + 4);
      }
      #pragma unroll
      for (int j = 0; j < 4; ++j) {
        f32x4 bc = *(const f32x4*)(&sBC[cur][l4 + j][4 * k16]);  // {B0,B1,C0,C1}
        float dA0 = exp2f(dv4[j] * Adn0);
        float dA1 = exp2f(dv4[j] * Adn1);
        h0 = fmaf(dA0, h0, g4[j] * bc[0]);
        h1 = fmaf(dA1, h1, g4[j] * bc[1]);
        float p = fmaf(h1, bc[3], h0 * bc[2]);
        p = dpp_add<0x111, 0xf, true>(p);      // row_shr 1/2/4/8: lane15 of each
        p = dpp_add<0x112, 0xf, true>(p);      // 16-lane group gets full sum
        p = dpp_add<0x114, 0xf, true>(p);
        p = dpp_add<0x118, 0xf, true>(p);
        if (writer) yp[(size_t)(lg + j) * 1024] = p;
      }
      dv4 = dv4n; g4 = g4n;
    }
    if (c + 1 < NC) {
      write_chunk(cur ^ 1);
      __syncthreads();
    }
  }
}

// ---------------- y_final = (y + u*D) * silu(z) -> bf16 ----------------
__global__ __launch_bounds__(256) void k_yfinal(const float* __restrict__ y,
    const u16* __restrict__ u, const u16* __restrict__ xz,
    const float* __restrict__ Dv, u16* __restrict__ yb) {
  int i = blockIdx.x * 256 + threadIdx.x;       // 8192*256 (4 elems each)
  int m = i >> 8, d = (i & 255) * 4;
  f32x4 yv = *(const f32x4*)(y + (size_t)m * 1024 + d);
  u16x4 uv = *(const u16x4*)(u + (size_t)m * 1024 + d);
  u16x4 zv = *(const u16x4*)(xz + (size_t)m * 2048 + 1024 + d);
  f32x4 Dw = *(const f32x4*)(Dv + d);
  u16x4 o;
  #pragma unroll
  for (int t = 0; t < 4; ++t) {
    float z = bf2f(zv[t]);
    float val = (yv[t] + bf2f(uv[t]) * Dw[t]) * (z * sigmoidf_(z));
    o[t] = f2bf(val);
  }
  *(u16x4*)(yb + (size_t)m * 1024 + d) = o;
}

extern "C" void kernel_launch(void* const* d_in, const int* in_sizes, int n_in,
                              void* d_out, int out_size, void* d_ws, size_t ws_size,
                              hipStream_t stream) {
  const float* x    = (const float*)d_in[0];
  const float* nw   = (const float*)d_in[1];
  const float* nb   = (const float*)d_in[2];
  const float* win  = (const float*)d_in[3];
  const float* cw   = (const float*)d_in[4];
  const float* cb   = (const float*)d_in[5];
  const float* wxp  = (const float*)d_in[6];
  const float* wdt  = (const float*)d_in[7];
  const float* dtb  = (const float*)d_in[8];
  const float* alog = (const float*)d_in[9];
  const float* Dv   = (const float*)d_in[10];
  const float* wout = (const float*)d_in[11];
  float* out = (float*)d_out;

  char* p = (char*)d_ws;
  auto alloc = [&](size_t bytes) { char* r = p; p += (bytes + 255) & ~(size_t)255; return r; };
  u16*   xn    = (u16*)  alloc((size_t)8192 * 256 * 2);
  u16*   winb  = (u16*)  alloc((size_t)2048 * 256 * 2);
  u16*   wxpb  = (u16*)  alloc((size_t)80 * 1024 * 2);
  u16*   wdtb  = (u16*)  alloc((size_t)1024 * 32 * 2);
  u16*   woutb = (u16*)  alloc((size_t)256 * 1024 * 2);
  u16*   xz    = (u16*)  alloc((size_t)8192 * 2048 * 2);  // [u | z] bf16
  u16*   ub    = (u16*)  alloc((size_t)8192 * 1024 * 2);  // silu(conv(u)) bf16
  u16*   dtbf  = (u16*)  alloc((size_t)8192 * 16 * 2);
  float* bcbuf = (float*)alloc((size_t)8 * 1024 * 64 * 4);       // [b][l][pair-interleaved B,C]
  float* dTgT  = (float*)alloc((size_t)2 * 8192 * 1024 * 4);     // deltaT | gT (64 MB)
  float* ysc   = (float*)alloc((size_t)8192 * 1024 * 4);
  u16*   ybf   = (u16*)  alloc((size_t)8192 * 1024 * 2);

  // weight casts (every call: ws is re-poisoned)
  k_cast<<<2048, 256, 0, stream>>>(win, winb, 2048 * 256);
  k_cast<<<320, 256, 0, stream>>>(wxp, wxpb, 80 * 1024);
  k_pad_dtw<<<128, 256, 0, stream>>>(wdt, wdtb);
  k_cast<<<1024, 256, 0, stream>>>(wout, woutb, 256 * 1024);

  // 1. LayerNorm
  k_ln<<<2048, 256, 0, stream>>>(x, nw, nb, xn);
  // 2. in_proj: (8192,256)x(2048,256)^T -> xz bf16 (8192,2048)
  k_gemm<2, 2, 4, 4, 1><<<dim3(64, 16), 256, 0, stream>>>(xn, winb, nullptr, xz, nullptr,
                                                          256, 256, 2048, 8, 256);
  // 3. conv + SiLU -> u bf16 (8192,1024)
  k_conv<<<32768, 256, 0, stream>>>(xz, cw, cb, ub);
  // 4. x_proj: (8192,1024)x(80,1024)^T -> dtbf bf16 + BC[b][l][pairs] fp32
  k_gemm<2, 1, 1, 5, 4><<<dim3(256, 1), 128, 0, stream>>>(ub, wxpb, bcbuf, dtbf, nullptr,
                                                          1024, 1024, 80, 32, 1024);
  // 5. dt_proj (K=16 padded to 32) + softplus -> deltaT[d][m], gT[d][m]=delta*u
  k_gemm<2, 2, 4, 4, 5><<<dim3(64, 8), 256, 0, stream>>>(dtbf, wdtb, dTgT, ub, dtb,
                                                         16, 32, 8192, 1, 16);
  // 6. selective scan -> y fp32 (8192,1024); 512 blocks = 8 b x 64 dblk
  k_scan<<<512, 256, 0, stream>>>(dTgT, dTgT + 8388608, bcbuf, alog, ysc);
  // 7. (y + u*D) * silu(z) -> bf16
  k_yfinal<<<8192, 256, 0, stream>>>(ysc, ub, xz, Dv, ybf);
  // 8. out_proj + residual -> d_out fp32 (8192,256)
  k_gemm<2, 2, 2, 2, 3><<<dim3(128, 4), 256, 0, stream>>>(ybf, woutb, out, nullptr, x,
                                                          1024, 1024, 256, 32, 1024);
}

// Round 8
// 365.270 us; speedup vs baseline: 1.3339x; 1.1312x over previous
//
#include <hip/hip_runtime.h>
#include <hip/hip_bf16.h>
#include <math.h>

// Shapes: B=8, L=1024, D_MODEL=256, D_INNER=1024, D_STATE=32, D_CONV=8, DT_RANK=16
// BL = 8192 token rows. GEMMs: bf16 MFMA 16x16x32, fp32 accumulate.
// Scan: chunk-parallel (NCH=32 chunks of CL=32), thread-per-d, 3 phases.

typedef float          f32x4 __attribute__((ext_vector_type(4)));
typedef float          f32x2 __attribute__((ext_vector_type(2)));
typedef short          s16x8 __attribute__((ext_vector_type(8)));
typedef unsigned short u16;
typedef u16            u16x4 __attribute__((ext_vector_type(4)));

#define DEV __device__ __forceinline__

#if defined(__has_builtin)
#  if __has_builtin(__builtin_amdgcn_exp2f)
#    define HAVE_EXP2 1
#  endif
#endif
#ifdef HAVE_EXP2
#  define ADN_SCALE 1.442695040888963f          // fold log2(e) into AdnT
DEV float fexp(float x) { return __builtin_amdgcn_exp2f(x); }   // raw v_exp_f32
#else
#  define ADN_SCALE 1.0f
DEV float fexp(float x) { return __expf(x); }                   // v_mul + v_exp
#endif

DEV float bf2f(u16 u) { unsigned int i = ((unsigned int)u) << 16; return __builtin_bit_cast(float, i); }
DEV u16 f2bf(float f) {
  unsigned int x = __builtin_bit_cast(unsigned int, f);
  unsigned int r = (x + 0x7FFFu + ((x >> 16) & 1u)) >> 16;   // RNE
  return (u16)r;
}
DEV float sigmoidf_(float x) { return 1.0f / (1.0f + __expf(-x)); }

// ---------------- small cast kernels ----------------
__global__ void k_cast(const float* __restrict__ s, u16* __restrict__ d, int n) {
  int i = blockIdx.x * 256 + threadIdx.x;
  if (i < n) d[i] = f2bf(s[i]);
}
// dt_proj_w (1024,16) -> bf16 (1024,32) zero-padded in K
__global__ void k_pad_dtw(const float* __restrict__ s, u16* __restrict__ d) {
  int i = blockIdx.x * 256 + threadIdx.x;   // 1024*32
  int row = i >> 5, k = i & 31;
  d[i] = (k < 16) ? f2bf(s[row * 16 + k]) : (u16)0;
}
// AdnT[n][d] = -exp(A_log[d][n]) * ADN_SCALE  (transposed, coalesced consumers)
__global__ void k_prep_adn(const float* __restrict__ alog, float* __restrict__ AdnT) {
  int i = blockIdx.x * 256 + threadIdx.x;   // 32*1024
  int n = i >> 10, d = i & 1023;
  AdnT[i] = -__expf(alog[d * 32 + n]) * ADN_SCALE;
}

// ---------------- LayerNorm: x fp32 (8192,256) -> xn bf16 ----------------
__global__ __launch_bounds__(256) void k_ln(const float* __restrict__ x,
    const float* __restrict__ w, const float* __restrict__ b, u16* __restrict__ xn) {
  int row  = blockIdx.x * 4 + (threadIdx.x >> 6);  // one wave per row
  int lane = threadIdx.x & 63;
  const float* xr = x + (size_t)row * 256 + lane * 4;
  f32x4 v = *(const f32x4*)xr;
  float s  = v[0] + v[1] + v[2] + v[3];
  float s2 = v[0]*v[0] + v[1]*v[1] + v[2]*v[2] + v[3]*v[3];
  for (int off = 32; off; off >>= 1) { s += __shfl_xor(s, off); s2 += __shfl_xor(s2, off); }
  float mu  = s * (1.0f / 256.0f);
  float inv = rsqrtf(s2 * (1.0f / 256.0f) - mu * mu + 1e-5f);
  int c = lane * 4;
  u16x4 o;
  #pragma unroll
  for (int t = 0; t < 4; ++t) o[t] = f2bf((v[t] - mu) * inv * w[c + t] + b[c + t]);
  *(u16x4*)(xn + (size_t)row * 256 + c) = o;
}

// ---------------- generic bf16 MFMA GEMM: C[M,N] = A[M,K] * W[N,K]^T ----------------
// EPI: 1 = bf16 out, 2 = softplus(acc + bias[col]) fp32, 3 = acc + resid fp32,
//      4 = x_proj scatter: gc<16 -> dtbf bf16 [m][16];
//          16<=gc<48 (B, n=gc-16) -> BC[b][l][4*(n>>1) + (n&1)];
//          48<=gc<80 (C, n=gc-48) -> BC[b][l][4*(n>>1) + 2 + (n&1)]
template<int WAVES_M, int WAVES_N, int WM, int WN, int EPI>
__global__ __launch_bounds__(WAVES_M * WAVES_N * 64)
void k_gemm(const u16* __restrict__ A, const u16* __restrict__ Bw,
            float* __restrict__ Cf, u16* __restrict__ Cb,
            const float* __restrict__ extra,
            int lda, int ldb, int ldc, int Ktiles, int Kact) {
  constexpr int BM = WAVES_M * WM * 16;
  constexpr int BN = WAVES_N * WN * 16;
  constexpr int BK = 32, LDP = BK + 8;            // +8 shorts: 80B row stride, kills bank conflicts
  constexpr int THREADS = WAVES_M * WAVES_N * 64;
  __shared__ u16 As[BM][LDP];
  __shared__ u16 Bs[BN][LDP];
  const int tid = threadIdx.x;
  const int m0 = blockIdx.x * BM, n0 = blockIdx.y * BN;
  const int w = tid >> 6, lane = tid & 63;
  const int wm = w / WAVES_N, wn = w % WAVES_N;
  const int r = lane & 15, kg = lane >> 4, ks = kg * 8;

  f32x4 acc[WM][WN] = {};

  for (int kt = 0; kt < Ktiles; ++kt) {
    const int k0 = kt * BK;
    for (int ci = tid; ci < BM * 4; ci += THREADS) {       // stage A tile (guarded for Kact<K)
      int row = ci >> 2, k8 = (ci & 3) * 8;
      s16x8 vv = {0, 0, 0, 0, 0, 0, 0, 0};
      if (k0 + k8 < Kact)
        vv = *(const s16x8*)(A + (size_t)(m0 + row) * lda + k0 + k8);
      *(s16x8*)(&As[row][k8]) = vv;
    }
    for (int ci = tid; ci < BN * 4; ci += THREADS) {       // stage B tile
      int row = ci >> 2, k8 = (ci & 3) * 8;
      *(s16x8*)(&Bs[row][k8]) = *(const s16x8*)(Bw + (size_t)(n0 + row) * ldb + k0 + k8);
    }
    __syncthreads();
    s16x8 af[WM], bfr[WN];
    #pragma unroll
    for (int i = 0; i < WM; ++i) af[i]  = *(const s16x8*)(&As[wm * WM * 16 + i * 16 + r][ks]);
    #pragma unroll
    for (int j = 0; j < WN; ++j) bfr[j] = *(const s16x8*)(&Bs[wn * WN * 16 + j * 16 + r][ks]);
    #pragma unroll
    for (int i = 0; i < WM; ++i)
      #pragma unroll
      for (int j = 0; j < WN; ++j)
        acc[i][j] = __builtin_amdgcn_mfma_f32_16x16x32_bf16(af[i], bfr[j], acc[i][j], 0, 0, 0);
    __syncthreads();
  }

  #pragma unroll
  for (int i = 0; i < WM; ++i)
    #pragma unroll
    for (int j = 0; j < WN; ++j)
      #pragma unroll
      for (int q = 0; q < 4; ++q) {
        int gr = m0 + wm * WM * 16 + i * 16 + kg * 4 + q;  // C/D: row=(lane>>4)*4+reg
        int gc = n0 + wn * WN * 16 + j * 16 + r;           //       col=lane&15
        float v = acc[i][j][q];
        size_t idx = (size_t)gr * ldc + gc;
        if constexpr (EPI == 1) Cb[idx] = f2bf(v);
        else if constexpr (EPI == 2) {
          v += extra[gc];
          v = (v > 20.0f) ? v : log1pf(expf(v));           // softplus -> delta [m][1024]
          Cf[idx] = v;
        } else if constexpr (EPI == 3) Cf[idx] = v + extra[idx];
        else if constexpr (EPI == 4) {
          int b_ = gr >> 10, l_ = gr & 1023;
          if (gc < 16)      Cb[(size_t)gr * 16 + gc] = f2bf(v);
          else if (gc < 48) {
            int n_ = gc - 16;
            Cf[(size_t)b_ * 65536 + (size_t)l_ * 64 + 4 * (n_ >> 1) + (n_ & 1)] = v;
          } else {
            int n_ = gc - 48;
            Cf[(size_t)b_ * 65536 + (size_t)l_ * 64 + 4 * (n_ >> 1) + 2 + (n_ & 1)] = v;
          }
        }
      }
}

// ---------------- causal depthwise conv (K=8) + bias + SiLU ----------------
__global__ __launch_bounds__(256) void k_conv(const u16* __restrict__ xz,
    const float* __restrict__ cw, const float* __restrict__ cb, u16* __restrict__ u) {
  int d = (blockIdx.x & 3) * 256 + threadIdx.x;
  int m = blockIdx.x >> 2;
  int l = m & 1023;
  const f32x4* wv = (const f32x4*)(cw + (size_t)d * 8);
  f32x4 w0 = wv[0], w1 = wv[1];
  float acc = cb[d];
  #pragma unroll
  for (int j = 0; j < 8; ++j) {
    int li = l - 7 + j;
    float wj = (j < 4) ? w0[j] : w1[j - 4];
    if (li >= 0) acc = fmaf(bf2f(xz[(size_t)(m - 7 + j) * 2048 + d]), wj, acc);
  }
  u[(size_t)m * 1024 + d] = f2bf(acc * sigmoidf_(acc));
}

// ================= chunk-parallel selective scan =================
// NCH=32 chunks of CL=32. Identity: prod_{l in c} dA_l = exp(Adn * sum dv).
constexpr int NCH = 32, CL = 32;

// Phase A: per (b, chunk, dgroup) local scan from h=0 (thread-per-d, h[32] in VGPR).
// Writes y_local[m][d], hend[b][c][n][d], Sc[b][c][d].
__global__ __launch_bounds__(256) void k_scanA(const float* __restrict__ delta,
    const u16* __restrict__ u, const float* __restrict__ BC,
    const float* __restrict__ AdnT, float* __restrict__ ylocal,
    float* __restrict__ hend, float* __restrict__ Sc) {
  __shared__ float sBC[CL][64];     // whole chunk of B/C rows: 8 KB
  const int blk = blockIdx.x;       // 8 b * 32 c * 4 dg
  const int b = blk >> 7, c = (blk >> 2) & 31, dg = blk & 3;
  const int t = threadIdx.x;
  const int d = dg * 256 + t;
  const int l0 = c * CL;
  {   // stage BC chunk once (rows l0..l0+31, 64 floats each)
    const float* src = BC + (size_t)b * 65536 + (size_t)l0 * 64;
    int row = t >> 3, col = (t & 7) * 8;
    *(f32x4*)&sBC[row][col]     = *(const f32x4*)(src + row * 64 + col);
    *(f32x4*)&sBC[row][col + 4] = *(const f32x4*)(src + row * 64 + col + 4);
  }
  float Adn[32];
  #pragma unroll
  for (int n = 0; n < 32; ++n) Adn[n] = AdnT[n * 1024 + d];
  __syncthreads();

  float h[32] = {};
  float S = 0.0f;
  const size_t base = ((size_t)b * 1024 + l0) * 1024 + d;
  #pragma unroll 2
  for (int l = 0; l < CL; ++l) {
    float dv = delta[base + (size_t)l * 1024];
    float g  = dv * bf2f(u[base + (size_t)l * 1024]);
    S += dv;
    float y = 0.0f;
    #pragma unroll
    for (int k = 0; k < 16; ++k) {
      f32x4 bc = *(const f32x4*)&sBC[l][4 * k];   // broadcast read (free)
      float dA0 = fexp(dv * Adn[2 * k]);
      float dA1 = fexp(dv * Adn[2 * k + 1]);
      h[2 * k]     = fmaf(dA0, h[2 * k],     g * bc[0]);
      h[2 * k + 1] = fmaf(dA1, h[2 * k + 1], g * bc[1]);
      y = fmaf(h[2 * k], bc[2], y);
      y = fmaf(h[2 * k + 1], bc[3], y);
    }
    ylocal[base + (size_t)l * 1024] = y;
  }
  const size_t co = (((size_t)b * NCH + c) * 32) * 1024 + d;
  #pragma unroll
  for (int n = 0; n < 32; ++n) hend[co + (size_t)n * 1024] = h[n];
  Sc[((size_t)b * NCH + c) * 1024 + d] = S;
}

// Phase B: per (b,n,d) sequential combine over chunks. In-place slot shift:
// after this kernel, hend slot c holds hstart[c+1] (state entering chunk c+1).
__global__ __launch_bounds__(256) void k_scanB(float* __restrict__ hend,
    const float* __restrict__ Sc, const float* __restrict__ AdnT) {
  const int blk = blockIdx.x;       // 8 b * 32 n * 4 dg
  const int b = blk >> 7, n = (blk >> 2) & 31, dg = blk & 3;
  const int d = dg * 256 + threadIdx.x;
  const float Adn = AdnT[n * 1024 + d];
  float hs = 0.0f;
  for (int c = 0; c < NCH - 1; ++c) {
    size_t idx = (((size_t)b * NCH + c) * 32 + n) * 1024 + d;
    float tmp = hend[idx];                                  // hend[c] (read before write)
    float e = fexp(Adn * Sc[((size_t)b * NCH + c) * 1024 + d]);
    hs = fmaf(e, hs, tmp);                                  // hstart[c+1]
    hend[idx] = hs;                                         // store into slot c
  }
}

// Phase C: y = y_local + sum_n C_n * exp(Adn_n * S_l) * hstart_n, then fused
// y_final = (y + u*D) * silu(z) -> bf16.  hstart for chunk c is at hend slot c-1.
__global__ __launch_bounds__(256) void k_scanC(const float* __restrict__ delta,
    const float* __restrict__ ylocal, const float* __restrict__ hend,
    const float* __restrict__ BC, const float* __restrict__ AdnT,
    const u16* __restrict__ u, const u16* __restrict__ xz,
    const float* __restrict__ Dv, u16* __restrict__ yb) {
  __shared__ float sBC[CL][64];
  const int blk = blockIdx.x;       // 8 b * 32 c * 4 dg
  const int b = blk >> 7, c = (blk >> 2) & 31, dg = blk & 3;
  const int t = threadIdx.x;
  const int d = dg * 256 + t;
  const int l0 = c * CL;
  {
    const float* src = BC + (size_t)b * 65536 + (size_t)l0 * 64;
    int row = t >> 3, col = (t & 7) * 8;
    *(f32x4*)&sBC[row][col]     = *(const f32x4*)(src + row * 64 + col);
    *(f32x4*)&sBC[row][col + 4] = *(const f32x4*)(src + row * 64 + col + 4);
  }
  float Adn[32], hs[32];
  #pragma unroll
  for (int n = 0; n < 32; ++n) Adn[n] = AdnT[n * 1024 + d];
  if (c > 0) {
    const size_t ho = (((size_t)b * NCH + (c - 1)) * 32) * 1024 + d;
    #pragma unroll
    for (int n = 0; n < 32; ++n) hs[n] = hend[ho + (size_t)n * 1024];
  } else {
    #pragma unroll
    for (int n = 0; n < 32; ++n) hs[n] = 0.0f;
  }
  __syncthreads();

  const float Dd = Dv[d];
  const size_t base = ((size_t)b * 1024 + l0) * 1024 + d;
  float S = 0.0f;
  #pragma unroll 2
  for (int l = 0; l < CL; ++l) {
    float dv = delta[base + (size_t)l * 1024];
    S += dv;
    float corr = 0.0f;
    if (c > 0) {                                   // block-uniform branch
      #pragma unroll
      for (int k = 0; k < 16; ++k) {
        f32x4 bc = *(const f32x4*)&sBC[l][4 * k];
        float e0 = fexp(S * Adn[2 * k]);
        float e1 = fexp(S * Adn[2 * k + 1]);
        corr = fmaf(e0 * hs[2 * k],     bc[2], corr);
        corr = fmaf(e1 * hs[2 * k + 1], bc[3], corr);
      }
    }
    float uv = bf2f(u[base + (size_t)l * 1024]);
    float z  = bf2f(xz[((size_t)(b * 1024 + l0 + l)) * 2048 + 1024 + d]);
    float yv = ylocal[base + (size_t)l * 1024] + corr;
    float val = (yv + uv * Dd) * (z * sigmoidf_(z));
    yb[base + (size_t)l * 1024] = f2bf(val);
  }
}

extern "C" void kernel_launch(void* const* d_in, const int* in_sizes, int n_in,
                              void* d_out, int out_size, void* d_ws, size_t ws_size,
                              hipStream_t stream) {
  const float* x    = (const float*)d_in[0];
  const float* nw   = (const float*)d_in[1];
  const float* nb   = (const float*)d_in[2];
  const float* win  = (const float*)d_in[3];
  const float* cw   = (const float*)d_in[4];
  const float* cb   = (const float*)d_in[5];
  const float* wxp  = (const float*)d_in[6];
  const float* wdt  = (const float*)d_in[7];
  const float* dtb  = (const float*)d_in[8];
  const float* alog = (const float*)d_in[9];
  const float* Dv   = (const float*)d_in[10];
  const float* wout = (const float*)d_in[11];
  float* out = (float*)d_out;

  char* p = (char*)d_ws;
  auto alloc = [&](size_t bytes) { char* r = p; p += (bytes + 255) & ~(size_t)255; return r; };
  u16*   xn    = (u16*)  alloc((size_t)8192 * 256 * 2);          // 4 MB (dead after in_proj)
  u16*   winb  = (u16*)  alloc((size_t)2048 * 256 * 2);
  u16*   wxpb  = (u16*)  alloc((size_t)80 * 1024 * 2);
  u16*   wdtb  = (u16*)  alloc((size_t)1024 * 32 * 2);
  u16*   woutb = (u16*)  alloc((size_t)256 * 1024 * 2);
  u16*   xz    = (u16*)  alloc((size_t)8192 * 2048 * 2);  // [u | z] bf16
  u16*   ub    = (u16*)  alloc((size_t)8192 * 1024 * 2);  // silu(conv(u)) bf16
  u16*   dtbf  = (u16*)  alloc((size_t)8192 * 16 * 2);
  float* bcbuf = (float*)alloc((size_t)8 * 1024 * 64 * 4);       // [b][l][pair-interleaved B,C]
  float* dl    = (float*)alloc((size_t)2 * 8192 * 1024 * 4);     // delta (32MB) | hend (32MB)
  float* ysc   = (float*)alloc((size_t)8192 * 1024 * 4);         // y_local
  u16*   ybf   = (u16*)  alloc((size_t)8192 * 1024 * 2);
  float* delta = dl;
  float* hend  = dl + (size_t)8192 * 1024;
  // carved from dead xn region (written only after in_proj consumed xn):
  float* AdnT  = (float*)xn;                       // 32*1024 f32 = 128 KB
  float* Sc    = (float*)xn + 32768;               // 8*32*1024 f32 = 1 MB

  // weight casts (every call: ws is re-poisoned)
  k_cast<<<2048, 256, 0, stream>>>(win, winb, 2048 * 256);
  k_cast<<<320, 256, 0, stream>>>(wxp, wxpb, 80 * 1024);
  k_pad_dtw<<<128, 256, 0, stream>>>(wdt, wdtb);
  k_cast<<<1024, 256, 0, stream>>>(wout, woutb, 256 * 1024);

  // 1. LayerNorm
  k_ln<<<2048, 256, 0, stream>>>(x, nw, nb, xn);
  // 2. in_proj: (8192,256)x(2048,256)^T -> xz bf16 (8192,2048)
  k_gemm<2, 2, 4, 4, 1><<<dim3(64, 16), 256, 0, stream>>>(xn, winb, nullptr, xz, nullptr,
                                                          256, 256, 2048, 8, 256);
  // (xn now dead -> AdnT/Sc may be written)
  k_prep_adn<<<128, 256, 0, stream>>>(alog, AdnT);
  // 3. conv + SiLU -> u bf16 (8192,1024)
  k_conv<<<32768, 256, 0, stream>>>(xz, cw, cb, ub);
  // 4. x_proj: (8192,1024)x(80,1024)^T -> dtbf bf16 + BC[b][l][pairs] fp32
  k_gemm<2, 1, 1, 5, 4><<<dim3(256, 1), 128, 0, stream>>>(ub, wxpb, bcbuf, dtbf, nullptr,
                                                          1024, 1024, 80, 32, 1024);
  // 5. dt_proj (K=16 padded to 32) + softplus -> delta fp32 [m][1024]
  k_gemm<2, 2, 4, 4, 2><<<dim3(64, 8), 256, 0, stream>>>(dtbf, wdtb, delta, nullptr, dtb,
                                                         16, 32, 1024, 1, 16);
  // 6. chunk-parallel scan
  k_scanA<<<1024, 256, 0, stream>>>(delta, ub, bcbuf, AdnT, ysc, hend, Sc);
  k_scanB<<<1024, 256, 0, stream>>>(hend, Sc, AdnT);
  k_scanC<<<1024, 256, 0, stream>>>(delta, ysc, hend, bcbuf, AdnT, ub, xz, Dv, ybf);
  // 7. out_proj + residual -> d_out fp32 (8192,256)
  k_gemm<2, 2, 2, 2, 3><<<dim3(128, 4), 256, 0, stream>>>(ybf, woutb, out, nullptr, x,
                                                          1024, 1024, 256, 32, 1024);
}